// Round 2
// 358.298 us; speedup vs baseline: 1.1085x; 1.1085x over previous
//
#include <hip/hip_runtime.h>
#include <hip/hip_fp16.h>

// PostGammaDenoise fused single-kernel guided filter, r=8 (17x17 box), eps=0.005.
// Halo-recompute (exact under reflect padding).
// This revision: tile 64x64 out (staged 96x96), 512 threads.
//   - halo overlap 3.0x -> 2.25x (staging reads 604 -> 453 MB logical)
//   - phase A interior + phase E use float4 RGB I/O (3x dwordx4 per 4 px,
//     was 12 scalar dwords) -> 4x fewer VMEM instrs, 4x bytes in flight
//   - epilogue stores non-temporal (output never re-read; keep L2 for halo)
//   - phase B single pass at 480/512 util (was 288 tasks on 256 thr = 2 passes)
// LDS 57,024 B -> 2 blocks/CU x 8 waves = 16 waves/CU (same 50% cap as the
// previous 34,816 B / 4-block config; occupancy unchanged, work and VMEM down).

#define HH 4096
#define WW 4096
#define TW 64            // output tile width
#define TH 64            // output tile height
#define SW 96            // staged cols = TW + 32
#define SH 96            // staged rows = TH + 32
#define SYS 98           // sY stride in halfs: even (aligned half2 writes), 49 dwords odd -> conflict-free
#define HIS 81           // hIhII / ab stride in half2s (odd dwords -> conflict-free)
#define HAS 65           // hAhB stride in half2s
#define INV289 (1.0f / 289.0f)
#define EPSV 0.005f

#define R1BYTES 25920    // max(sY 96*98*2 = 18,816 ; ab 80*81*4 = 25,920)
#define R2BYTES 31104    // max(hIhII 96*81*4 = 31,104 ; hAhB 80*65*4 = 20,800)

typedef float f32x4 __attribute__((ext_vector_type(4)));   // native vec for nontemporal builtin

__device__ __forceinline__ int reflect_idx(int i, int n) {
    i = (i < 0) ? -i : i;
    i = (i >= n) ? (2 * n - 2 - i) : i;
    return i;
}

__global__ __launch_bounds__(512, 4) void gf_fused(const float* __restrict__ x,
                                                   float* __restrict__ out) {
    // Overlay plan (barrier-separated lifetimes):
    //   region1 [0, 25920):        sY (phase A..B)   then ab   (written C, read D)
    //   region2 [25920, 57024):    hIhII (B..C)      then hAhB (written D, read E)
    __shared__ __align__(16) char smem[R1BYTES + R2BYTES];
    __half*  sY    = (__half*)smem;
    __half2* ab    = (__half2*)smem;
    __half2* hIhII = (__half2*)(smem + R1BYTES);
    __half2* hAhB  = (__half2*)(smem + R1BYTES);

    const int t = threadIdx.x;
    const int tx = blockIdx.x * TW;
    const int ty = blockIdx.y * TH;

    // ---- Phase A: stage luma (fp16) for the 96x96 halo region ----
    // 96 rows x 24 col-groups of 4 px = 2304 tasks. Interior: 3 float4 loads
    // per task (48 B contiguous per lane, 16-B aligned since tx%64==0).
    {
        const bool interior = (tx >= 16) & (tx + SW - 16 <= WW) &
                              (ty >= 16) & (ty + SH - 16 <= HH);
        if (interior) {
            for (int task = t; task < SH * 24; task += 512) {
                int r = task / 24;
                int g = task - r * 24;
                const float4* p = (const float4*)(x + ((long)(ty + r - 16) * WW + (tx - 16 + 4 * g)) * 3);
                float4 f0 = p[0], f1 = p[1], f2 = p[2];
                float Y0 = 0.2126f * f0.x + 0.7152f * f0.y + 0.0722f * f0.z;
                float Y1 = 0.2126f * f0.w + 0.7152f * f1.x + 0.0722f * f1.y;
                float Y2 = 0.2126f * f1.z + 0.7152f * f1.w + 0.0722f * f2.x;
                float Y3 = 0.2126f * f2.y + 0.7152f * f2.z + 0.0722f * f2.w;
                __half2* q2 = (__half2*)&sY[r * SYS + 4 * g];   // even index -> 4B aligned
                q2[0] = __floats2half2_rn(Y0, Y1);
                q2[1] = __floats2half2_rn(Y2, Y3);
            }
        } else {
            for (int task = t; task < SH * 24; task += 512) {
                int r = task / 24;
                int g = task - r * 24;
                int gy = reflect_idx(ty + r - 16, HH);
                #pragma unroll
                for (int cc = 0; cc < 4; ++cc) {
                    int gx = reflect_idx(tx - 16 + 4 * g + cc, WW);
                    const float* p = x + ((long)gy * WW + gx) * 3;
                    float Yv = 0.2126f * p[0] + 0.7152f * p[1] + 0.0722f * p[2];
                    sY[r * SYS + 4 * g + cc] = __float2half_rn(Yv);
                }
            }
        }
    }
    __syncthreads();

    // ---- Phase B: horizontal box17 of (Y, Y^2): 96 rows x 5 segs of 16 ----
    // 480 tasks, single pass (94% util; was 2 passes at 56%).
    if (t < 480) {
        int r = t % 96;
        int s = t / 96;
        int base = r * SYS + s * 16;
        int ob = r * HIS + s * 16;
        float sI = 0.f, sII = 0.f;
        #pragma unroll
        for (int k = 0; k <= 16; ++k) {
            float w = __half2float(sY[base + k]);
            sI += w; sII += w * w;
        }
        hIhII[ob] = __floats2half2_rn(sI, sII);
        #pragma unroll
        for (int j = 1; j < 16; ++j) {
            float va = __half2float(sY[base + 16 + j]);
            float vs = __half2float(sY[base + j - 1]);
            sI  += va - vs;
            sII += va * va - vs * vs;
            hIhII[ob + j] = __floats2half2_rn(sI, sII);
        }
    }
    __syncthreads();

    // ---- Phase C: vertical box17 + a,b (80 rows x 80 cols) -> ab (over sY) ----
    if (t < 400) {
        int c = t % 80;
        int q = t / 80;          // 0..4, 16 rows each
        int r0 = q * 16;
        float sI = 0.f, sII = 0.f;
        #pragma unroll
        for (int k = 0; k <= 16; ++k) {
            float2 v = __half22float2(hIhII[(r0 + k) * HIS + c]);
            sI += v.x; sII += v.y;
        }
        #pragma unroll
        for (int j = 0; j < 16; ++j) {
            int o = r0 + j;
            float mI = sI * INV289;
            float mII = sII * INV289;
            float var = mII - mI * mI;
            float a = var * __builtin_amdgcn_rcpf(var + EPSV);   // err ~1e-7 << fp16 storage err
            float b = mI - a * mI;
            ab[o * HIS + c] = __floats2half2_rn(a, b);
            if (j < 15) {
                float2 va = __half22float2(hIhII[(o + 17) * HIS + c]);
                float2 vs = __half22float2(hIhII[o * HIS + c]);
                sI  += va.x - vs.x;
                sII += va.y - vs.y;
            }
        }
    }
    __syncthreads();

    // ---- Phase D: horizontal box17 of (a,b): 80 rows x 4 segs -> hAhB (over hIhII) ----
    if (t < 320) {
        int r = t % 80;
        int s = t / 80;          // 0..3
        int base = r * HIS + s * 16;
        int ob = r * HAS + s * 16;
        float sA = 0.f, sB = 0.f;
        #pragma unroll
        for (int k = 0; k <= 16; ++k) {
            float2 v = __half22float2(ab[base + k]);
            sA += v.x; sB += v.y;
        }
        hAhB[ob] = __floats2half2_rn(sA, sB);
        #pragma unroll
        for (int j = 1; j < 16; ++j) {
            float2 va = __half22float2(ab[base + 16 + j]);
            float2 vs = __half22float2(ab[base + j - 1]);
            sA += va.x - vs.x;
            sB += va.y - vs.y;
            hAhB[ob + j] = __floats2half2_rn(sA, sB);
        }
    }
    __syncthreads();

    // ---- Phase E: vertical box17 + epilogue, 4-px vectorized I/O ----
    // Thread owns 4 consecutive cols x 2 rows: 16 col-groups x 32 row-groups.
    {
        const int m  = t & 15;
        const int q  = t >> 4;       // 0..31
        const int r0 = q * 2;
        const int c0 = m * 4;
        float sA[4] = {0.f, 0.f, 0.f, 0.f};
        float sB[4] = {0.f, 0.f, 0.f, 0.f};
        #pragma unroll
        for (int k = 0; k <= 16; ++k) {
            int rb = (r0 + k) * HAS + c0;
            #pragma unroll
            for (int cc = 0; cc < 4; ++cc) {
                float2 v = __half22float2(hAhB[rb + cc]);
                sA[cc] += v.x; sB[cc] += v.y;
            }
        }
        #pragma unroll
        for (int j = 0; j < 2; ++j) {
            int o = r0 + j;
            long gbase = ((long)(ty + o) * WW + (tx + c0)) * 3;   // multiple of 4 floats
            const float4* p = (const float4*)(x + gbase);
            float4 f0 = p[0], f1 = p[1], f2 = p[2];
            float px[12] = {f0.x, f0.y, f0.z, f0.w, f1.x, f1.y,
                            f1.z, f1.w, f2.x, f2.y, f2.z, f2.w};
            float ov[12];
            #pragma unroll
            for (int cc = 0; cc < 4; ++cc) {
                float rr = px[3 * cc], gg = px[3 * cc + 1], bb = px[3 * cc + 2];
                float Y = 0.2126f * rr + 0.7152f * gg + 0.0722f * bb;
                float ma = sA[cc] * INV289;
                float mb = sB[cc] * INV289;
                float scale = (ma * Y + mb) * __builtin_amdgcn_rcpf(fmaxf(Y, 1e-6f));
                ov[3 * cc]     = fminf(fmaxf(rr * scale, 0.f), 1.f);
                ov[3 * cc + 1] = fminf(fmaxf(gg * scale, 0.f), 1.f);
                ov[3 * cc + 2] = fminf(fmaxf(bb * scale, 0.f), 1.f);
            }
            f32x4* qo = (f32x4*)(out + gbase);
            f32x4 s0 = {ov[0], ov[1], ov[2],  ov[3]};
            f32x4 s1 = {ov[4], ov[5], ov[6],  ov[7]};
            f32x4 s2 = {ov[8], ov[9], ov[10], ov[11]};
            __builtin_nontemporal_store(s0, qo);
            __builtin_nontemporal_store(s1, qo + 1);
            __builtin_nontemporal_store(s2, qo + 2);
            if (j == 0) {
                #pragma unroll
                for (int cc = 0; cc < 4; ++cc) {
                    float2 va = __half22float2(hAhB[(o + 17) * HAS + c0 + cc]);
                    float2 vs = __half22float2(hAhB[o * HAS + c0 + cc]);
                    sA[cc] += va.x - vs.x;
                    sB[cc] += va.y - vs.y;
                }
            }
        }
    }
}

extern "C" void kernel_launch(void* const* d_in, const int* in_sizes, int n_in,
                              void* d_out, int out_size, void* d_ws, size_t ws_size,
                              hipStream_t stream) {
    const float* x = (const float*)d_in[0];
    float* out = (float*)d_out;
    dim3 grid(WW / TW, HH / TH);   // 64 x 64 = 4096 blocks
    gf_fused<<<grid, 512, 0, stream>>>(x, out);
}